// Round 5
// baseline (350.060 us; speedup 1.0000x reference)
//
#include <hip/hip_runtime.h>

#define HH 16
#define SS 4096
#define DHD 128
#define BR 64         // q rows per block (16 per wave)
#define BC 64         // k/v rows per tile
#define LDQ 144       // bf16/row for K bufs (+Q staging): 288B — measured-good (3.46M)
#define LDV 68        // bf16/row for V^T bufs: 136B — measured-good
#define LDPT 72       // bf16/row for pT_s: 144B (16B-aligned)
#define LDOS 136      // f32/row for epilogue overlay: 544B (16B-aligned)
#define DM  (HH * DHD)

typedef __bf16 bf16x8_t __attribute__((ext_vector_type(8)));
typedef __bf16 bf16x4_t __attribute__((ext_vector_type(4)));
typedef float  f32x4_t  __attribute__((ext_vector_type(4)));

// LDS-only barrier: drain lgkmcnt but leave global prefetch loads in flight
// (plain __syncthreads emits s_waitcnt vmcnt(0) which kills the prefetch).
#define BAR() asm volatile("s_waitcnt lgkmcnt(0)\n\ts_barrier" ::: "memory")

__device__ __forceinline__ f32x4_t vmax4(f32x4_t a, f32x4_t b) {
    f32x4_t r;
    r[0] = fmaxf(a[0], b[0]); r[1] = fmaxf(a[1], b[1]);
    r[2] = fmaxf(a[2], b[2]); r[3] = fmaxf(a[3], b[3]);
    return r;
}

// (256,2): VGPR cap 128 (R1 showed arg=3 -> 84 + spill catastrophe).
// LDS 80896 x 2 blocks = 161792 <= 160KiB: 2 blocks/CU, double-buffered K/V.
__global__ __launch_bounds__(256, 2)
void fa_fwd(const float* __restrict__ q, const float* __restrict__ k,
            const float* __restrict__ v, float* __restrict__ out)
{
    // 512 blocks: q-tile pair {g, 63-g} -> 65 k-iters each (R2 scheduling, R0-proven).
    const int L = blockIdx.x;
    const int h = L & 15;
    const int g = L >> 4;
    const int qts[2] = { g, 63 - g };

    const int tid  = threadIdx.x;
    const int wave = tid >> 6;
    const int lane = tid & 63;
    const int l16  = lane & 15;
    const int quad = lane >> 4;
    const int rK   = tid >> 5;
    const int c4   = tid & 31;
    const int dbase = (wave & 1) * 64;
    const int rbase = (wave >> 1) * 32;

    // smem: [k0 18432][k1 18432][v0 17408][v1 17408][pT 9216] = 80896 B.
    // Double-buffered K/V: iter j reads buf[j&1], commits tile j+1 into buf[~j&1]
    // -> ONE lgkm-barrier per iteration; commit overlaps softmax VALU.
    // Q stages into k1 (consumed into regs before iter 0's commit writes k1).
    __shared__ __align__(16) char smem[80896];
    unsigned short* pT_s = (unsigned short*)(smem + 71680);
    float* os = (float*)smem;   // epilogue overlay (34816 B)

    const size_t hoff = (size_t)h * SS * DHD;
    const float* qh = q + hoff;
    const float* kh = k + hoff;
    const float* vh = v + hoff;

    float4 kreg[8];
    float  vreg[8][4];
    auto issue = [&](int j) {
        const float* kb = kh + (size_t)j * BC * DHD;
        #pragma unroll
        for (int i = 0; i < 8; ++i)
            kreg[i] = ((const float4*)(kb + (size_t)(rK + i * 8) * DHD))[c4];
        const float* vb = vh + (size_t)j * BC * DHD + dbase + lane;
        #pragma unroll
        for (int p = 0; p < 8; ++p) {
            const float* vp = vb + (size_t)(rbase + p * 4) * DHD;
            vreg[p][0] = vp[0];
            vreg[p][1] = vp[DHD];
            vreg[p][2] = vp[2 * DHD];
            vreg[p][3] = vp[3 * DHD];
        }
    };
    auto commit = [&](int b) {     // kreg/vreg -> K/V buffer b
        unsigned short* ks = (unsigned short*)(smem + b * 18432);
        unsigned short* vs = (unsigned short*)(smem + 36864 + b * 17408);
        #pragma unroll
        for (int i = 0; i < 8; ++i) {
            bf16x4_t bb;
            bb[0] = (__bf16)kreg[i].x; bb[1] = (__bf16)kreg[i].y;
            bb[2] = (__bf16)kreg[i].z; bb[3] = (__bf16)kreg[i].w;
            *(bf16x4_t*)&ks[(rK + i * 8) * LDQ + c4 * 4] = bb;
        }
        #pragma unroll
        for (int p = 0; p < 8; ++p) {
            bf16x4_t bb;
            bb[0] = (__bf16)vreg[p][0]; bb[1] = (__bf16)vreg[p][1];
            bb[2] = (__bf16)vreg[p][2]; bb[3] = (__bf16)vreg[p][3];
            *(bf16x4_t*)&vs[(dbase + lane) * LDV + rbase + p * 4] = bb;
        }
    };

    // 1/sqrt(128) * log2(e): softmax in exp2 domain.
    const float scale = 0.088388347648318447f * 1.4426950408889634f;
    issue(0);

    for (int t = 0; t < 2; ++t) {
        const int qt = qts[t];
        __syncthreads();               // prev tile's os reads done
        // ---- stage Q (scale folded) into k1 region ----
        unsigned short* q_s = (unsigned short*)(smem + 18432);
        #pragma unroll
        for (int i = 0; i < 8; ++i) {
            int idx = tid + i * 256;
            int r   = idx >> 5;
            int cc  = idx & 31;
            float4 val = ((const float4*)(qh + (size_t)(qt * BR + r) * DHD))[cc];
            bf16x4_t bb;
            bb[0] = (__bf16)(val.x * scale); bb[1] = (__bf16)(val.y * scale);
            bb[2] = (__bf16)(val.z * scale); bb[3] = (__bf16)(val.w * scale);
            *(bf16x4_t*)&q_s[r * LDQ + cc * 4] = bb;
        }
        __syncthreads();

        // ---- Q B-fragments (n-dim = wave's 16 q rows) ----
        bf16x8_t qf[4];
        #pragma unroll
        for (int kc = 0; kc < 4; ++kc)
            qf[kc] = *(const bf16x8_t*)
                &q_s[(wave * 16 + l16) * LDQ + kc * 32 + quad * 8];

        f32x4_t oacc[8];               // O^T: row=d (8 m-tiles), col=q=l16
        #pragma unroll
        for (int mt = 0; mt < 8; ++mt) oacc[mt] = (f32x4_t)(0.0f);
        float mi = -INFINITY, li = 0.0f;

        const int q_local = wave * 16 + l16;

        // ---- pipeline prologue: tile0 -> buf0; prefetch tile1 ----
        commit(0);
        if (qt >= 1)     issue(1);
        else if (t == 0) issue(0);     // qt==0: prefetch next q-tile's first k/v
        BAR();                         // qf reads + commit drained; vm in flight

        for (int j = 0; j <= qt; ++j) {
            const int br = j & 1;
            unsigned short* ks = (unsigned short*)(smem + br * 18432);
            unsigned short* vs = (unsigned short*)(smem + 36864 + br * 17408);

            // ---- S^T = K Q^T : 4 m-tiles (k-dim) x 1 n-tile (q) ----
            f32x4_t sa[4];
            #pragma unroll
            for (int mt = 0; mt < 4; ++mt) sa[mt] = (f32x4_t)(0.0f);
            __builtin_amdgcn_s_setprio(1);
            #pragma unroll
            for (int kc = 0; kc < 4; ++kc)
                #pragma unroll
                for (int mt = 0; mt < 4; ++mt) {
                    bf16x8_t kf = *(const bf16x8_t*)
                        &ks[(mt * 16 + l16) * LDQ + kc * 32 + quad * 8];
                    sa[mt] = __builtin_amdgcn_mfma_f32_16x16x32_bf16(kf, qf[kc], sa[mt], 0, 0, 0);
                }
            __builtin_amdgcn_s_setprio(0);

            // ---- commit tile j+1 into the other buffer; refill kreg/vreg ----
            // (ds_writes overlap the softmax VALU chain below; loads stay in flight
            //  across the end-of-iter lgkm-only barrier.)
            if (j < qt) {
                commit(br ^ 1);
                if (j + 2 <= qt) issue(j + 2);
                else if (t == 0) issue(0);   // fires once at j==qt-1: next q-tile
            }

            // ---- causal mask (diag tile only) ----
            if (j == qt) {
                #pragma unroll
                for (int mt = 0; mt < 4; ++mt)
                    #pragma unroll
                    for (int r = 0; r < 4; ++r)
                        if (mt * 16 + quad * 4 + r > q_local) sa[mt][r] = -INFINITY;
            }

            // ---- online softmax (exp2 domain): in-lane 16 + 2 shfls ----
            f32x4_t mv = vmax4(vmax4(sa[0], sa[1]), vmax4(sa[2], sa[3]));
            float mx = fmaxf(fmaxf(mv[0], mv[1]), fmaxf(mv[2], mv[3]));
            mx = fmaxf(mx, __shfl_xor(mx, 16));
            mx = fmaxf(mx, __shfl_xor(mx, 32));
            // defer-max (T13): skip rescale when max didn't grow past mi+8.
            const bool skip = __all((int)(mx <= mi + 8.0f)) != 0;
            const float mnew = skip ? mi : fmaxf(mi, mx);
            bf16x4_t pkv[4];
            #pragma unroll
            for (int mt = 0; mt < 4; ++mt) {
                #pragma unroll
                for (int r = 0; r < 4; ++r)
                    sa[mt][r] = __builtin_amdgcn_exp2f(sa[mt][r] - mnew);
                pkv[mt][0] = (__bf16)sa[mt][0]; pkv[mt][1] = (__bf16)sa[mt][1];
                pkv[mt][2] = (__bf16)sa[mt][2]; pkv[mt][3] = (__bf16)sa[mt][3];
            }
            f32x4_t sv = sa[0] + sa[1] + sa[2] + sa[3];
            float rs = (sv[0] + sv[1]) + (sv[2] + sv[3]);
            rs += __shfl_xor(rs, 16);
            rs += __shfl_xor(rs, 32);
            if (skip) {
                li += rs;
            } else {
                float a = __builtin_amdgcn_exp2f(mi - mnew);
                mi = mnew;
                li = li * a + rs;
                #pragma unroll
                for (int mt = 0; mt < 8; ++mt) {
                    oacc[mt][0] *= a; oacc[mt][1] *= a;
                    oacc[mt][2] *= a; oacc[mt][3] *= a;
                }
            }

            // ---- P (q-major) -> LDS: 4 x ds_write_b64, wave-local ----
            #pragma unroll
            for (int mt = 0; mt < 4; ++mt)
                *(bf16x4_t*)&pT_s[(wave * 16 + l16) * LDPT + mt * 16 + quad * 4] = pkv[mt];

            // ---- O^T += V^T P^T : 8 m-tiles (d) x 1 n-tile (q), k=64 ----
            __builtin_amdgcn_s_setprio(1);
            #pragma unroll
            for (int kc = 0; kc < 2; ++kc) {
                bf16x8_t pb = *(const bf16x8_t*)
                    &pT_s[(wave * 16 + l16) * LDPT + kc * 32 + quad * 8];
                #pragma unroll
                for (int mt = 0; mt < 8; ++mt) {
                    bf16x4_t vlo = *(const bf16x4_t*)
                        &vs[(mt * 16 + l16) * LDV + kc * 32 + quad * 8];
                    bf16x4_t vhi = *(const bf16x4_t*)
                        &vs[(mt * 16 + l16) * LDV + kc * 32 + quad * 8 + 4];
                    bf16x8_t vf = __builtin_shufflevector(vlo, vhi, 0,1,2,3,4,5,6,7);
                    oacc[mt] = __builtin_amdgcn_mfma_f32_16x16x32_bf16(vf, pb, oacc[mt], 0, 0, 0);
                }
            }
            __builtin_amdgcn_s_setprio(0);

            BAR();   // single per-iter barrier: commits visible, reads drained
        }

        // ---- epilogue: O^T -> LDS overlay -> coalesced fp32 store ----
        __syncthreads();               // all frag reads done before overlay
        float inv = 1.0f / li;
        #pragma unroll
        for (int mt = 0; mt < 8; ++mt)
            #pragma unroll
            for (int r = 0; r < 4; ++r)
                os[(wave * 16 + l16) * LDOS + mt * 16 + quad * 4 + r] = oacc[mt][r] * inv;
        __syncthreads();
        #pragma unroll
        for (int p = 0; p < 8; ++p) {
            int row = p * 8 + rK;
            float4 f4 = *(const float4*)&os[row * LDOS + c4 * 4];
            *(float4*)&out[(size_t)(qt * BR + row) * DM + h * DHD + c4 * 4] = f4;
        }
    }
}

extern "C" void kernel_launch(void* const* d_in, const int* in_sizes, int n_in,
                              void* d_out, int out_size, void* d_ws, size_t ws_size,
                              hipStream_t stream) {
    const float* q = (const float*)d_in[0];
    const float* k = (const float*)d_in[1];
    const float* v = (const float*)d_in[2];
    float* out = (float*)d_out;
    fa_fwd<<<dim3((SS / BR / 2) * HH), dim3(256), 0, stream>>>(q, k, v, out);
}

// Round 6
// 331.334 us; speedup vs baseline: 1.0565x; 1.0565x over previous
//
#include <hip/hip_runtime.h>

#define HH 16
#define SS 4096
#define DHD 128
#define BR 128        // q rows per block (16 per wave, 8 waves)
#define BC 64         // k/v rows per tile
#define LDQ 144       // bf16/row for k_s: 288B — measured-good (R0: 3.46M confl)
#define LDQS 136      // bf16/row for Q staging overlay (prologue only)
#define LDV 68        // bf16/row for vt_s: 136B — measured-good
#define LDPT 72       // bf16/row for pT_s: 144B (16B-aligned)
#define LDOS 136      // f32/row for epilogue overlay: 544B (16B-aligned)
#define DM  (HH * DHD)

typedef __bf16 bf16x8_t __attribute__((ext_vector_type(8)));
typedef __bf16 bf16x4_t __attribute__((ext_vector_type(4)));
typedef float  f32x4_t  __attribute__((ext_vector_type(4)));

// LDS-only barrier: drain lgkmcnt but leave global prefetch loads in flight
// (plain __syncthreads emits s_waitcnt vmcnt(0) which kills the prefetch).
#define BAR() asm volatile("s_waitcnt lgkmcnt(0)\n\ts_barrier" ::: "memory")

__device__ __forceinline__ f32x4_t vmax4(f32x4_t a, f32x4_t b) {
    f32x4_t r;
    r[0] = fmaxf(a[0], b[0]); r[1] = fmaxf(a[1], b[1]);
    r[2] = fmaxf(a[2], b[2]); r[3] = fmaxf(a[3], b[3]);
    return r;
}

// (512,2): empirical compiler rule cap = 256/arg -> 128 VGPR (R0/R1 data).
// Kernel live set ~112 (kreg/vreg halved vs R0) -> no spill expected.
// LDS 54272 x 2 = 108544 <= 160K -> 2 blocks/CU = 16 waves = 4 waves/SIMD.
__global__ __launch_bounds__(512, 2)
void fa_fwd(const float* __restrict__ q, const float* __restrict__ k,
            const float* __restrict__ v, float* __restrict__ out)
{
    // 512 blocks x 512 threads, one 128-row q-tile each.
    // L<256: qt=31-(L>>4) (long, dispatched first); L>=256: qt=(L>>4)-16 (short).
    // Round-robin gives each CU one long + one short: (2qt+2) sums to 66 iters.
    const int L  = blockIdx.x;
    const int h  = L & 15;
    const int i5 = L >> 4;                       // 0..31
    const int qt = (i5 < 16) ? (31 - i5) : (i5 - 16);
    const int jmax = 2 * qt + 1;

    const int tid  = threadIdx.x;
    const int wave = tid >> 6;                   // 0..7
    const int lane = tid & 63;
    const int l16  = lane & 15;
    const int quad = lane >> 4;
    const int rK   = tid >> 5;                   // 0..15
    const int c4   = tid & 31;
    const int dbase = (wave & 1) * 64;
    const int rbase = (wave >> 1) * 16;

    // smem: [k 18432][vt 17408][pT 18432] = 54272 B.
    // Q staging (34816 B) overlays k+vt (consumed into regs before first commit).
    // Epilogue os overlay (34816 B) also over k+vt, in two 64-row passes.
    __shared__ __align__(16) char smem[54272];
    unsigned short* k_s  = (unsigned short*)smem;
    unsigned short* vt_s = (unsigned short*)(smem + 18432);
    unsigned short* pT_s = (unsigned short*)(smem + 35840);
    unsigned short* q_s  = (unsigned short*)smem;
    float* os = (float*)smem;

    const size_t hoff = (size_t)h * SS * DHD;
    const float* qh = q + hoff;
    const float* kh = k + hoff;
    const float* vh = v + hoff;

    float4 kreg[4];                 // 16 VGPR (half of R0)
    float  vreg[4][4];              // 16 VGPR
    auto issue = [&](int j) {
        const float* kb = kh + (size_t)j * BC * DHD;
        #pragma unroll
        for (int i = 0; i < 4; ++i)
            kreg[i] = ((const float4*)(kb + (size_t)(rK + i * 16) * DHD))[c4];
        const float* vb = vh + (size_t)j * BC * DHD + dbase + lane;
        #pragma unroll
        for (int p = 0; p < 4; ++p) {
            const float* vp = vb + (size_t)(rbase + p * 4) * DHD;
            vreg[p][0] = vp[0];
            vreg[p][1] = vp[DHD];
            vreg[p][2] = vp[2 * DHD];
            vreg[p][3] = vp[3 * DHD];
        }
    };
    auto commit = [&]() {           // kreg/vreg -> k_s / vt_s (single buffer)
        #pragma unroll
        for (int i = 0; i < 4; ++i) {
            bf16x4_t bb;
            bb[0] = (__bf16)kreg[i].x; bb[1] = (__bf16)kreg[i].y;
            bb[2] = (__bf16)kreg[i].z; bb[3] = (__bf16)kreg[i].w;
            *(bf16x4_t*)&k_s[(rK + i * 16) * LDQ + c4 * 4] = bb;
        }
        #pragma unroll
        for (int p = 0; p < 4; ++p) {
            bf16x4_t bb;
            bb[0] = (__bf16)vreg[p][0]; bb[1] = (__bf16)vreg[p][1];
            bb[2] = (__bf16)vreg[p][2]; bb[3] = (__bf16)vreg[p][3];
            *(bf16x4_t*)&vt_s[(dbase + lane) * LDV + rbase + p * 4] = bb;
        }
    };

    // 1/sqrt(128) * log2(e): softmax in exp2 domain.
    const float scale = 0.088388347648318447f * 1.4426950408889634f;
    issue(0);

    // ---- stage Q (scale folded) into overlay ----
    #pragma unroll
    for (int i = 0; i < 8; ++i) {
        int idx = tid + i * 512;
        int r   = idx >> 5;                       // 0..127
        int cc  = idx & 31;
        float4 val = ((const float4*)(qh + (size_t)(qt * BR + r) * DHD))[cc];
        bf16x4_t bb;
        bb[0] = (__bf16)(val.x * scale); bb[1] = (__bf16)(val.y * scale);
        bb[2] = (__bf16)(val.z * scale); bb[3] = (__bf16)(val.w * scale);
        *(bf16x4_t*)&q_s[r * LDQS + cc * 4] = bb;
    }
    __syncthreads();

    // ---- Q B-fragments (n-dim = wave's 16 q rows) ----
    const int q_local = wave * 16 + l16;          // 0..127
    bf16x8_t qf[4];
    #pragma unroll
    for (int kc = 0; kc < 4; ++kc)
        qf[kc] = *(const bf16x8_t*)&q_s[q_local * LDQS + kc * 32 + quad * 8];

    f32x4_t oacc[8];                // O^T: row=d (8 m-tiles), col=q=l16
    #pragma unroll
    for (int mt = 0; mt < 8; ++mt) oacc[mt] = (f32x4_t)(0.0f);
    float mi = -INFINITY, li = 0.0f;

    for (int j = 0; j <= jmax; ++j) {
        BAR();                     // qf reads (j=0) / prev-iter LDS reads drained
        commit();
        if (j < jmax) issue(j + 1);
        BAR();

        // ---- S^T = K Q^T : 4 m-tiles (k-dim) x 1 n-tile (q) ----
        f32x4_t sa[4];
        #pragma unroll
        for (int mt = 0; mt < 4; ++mt) sa[mt] = (f32x4_t)(0.0f);
        __builtin_amdgcn_s_setprio(1);
        #pragma unroll
        for (int kc = 0; kc < 4; ++kc)
            #pragma unroll
            for (int mt = 0; mt < 4; ++mt) {
                bf16x8_t kf = *(const bf16x8_t*)
                    &k_s[(mt * 16 + l16) * LDQ + kc * 32 + quad * 8];
                sa[mt] = __builtin_amdgcn_mfma_f32_16x16x32_bf16(kf, qf[kc], sa[mt], 0, 0, 0);
            }
        __builtin_amdgcn_s_setprio(0);

        // ---- causal mask: diagonal spans k-tiles j=2qt, 2qt+1 ----
        if (j >= 2 * qt) {
            const int off = (j - 2 * qt) * 64;
            #pragma unroll
            for (int mt = 0; mt < 4; ++mt)
                #pragma unroll
                for (int r = 0; r < 4; ++r)
                    if (off + mt * 16 + quad * 4 + r > q_local) sa[mt][r] = -INFINITY;
        }

        // ---- online softmax (exp2 domain): in-lane 16 + 2 shfls ----
        f32x4_t mv = vmax4(vmax4(sa[0], sa[1]), vmax4(sa[2], sa[3]));
        float mx = fmaxf(fmaxf(mv[0], mv[1]), fmaxf(mv[2], mv[3]));
        mx = fmaxf(mx, __shfl_xor(mx, 16));
        mx = fmaxf(mx, __shfl_xor(mx, 32));
        // defer-max (T13): skip rescale when max didn't grow past mi+8.
        const bool skip = __all((int)(mx <= mi + 8.0f)) != 0;
        const float mnew = skip ? mi : fmaxf(mi, mx);
        bf16x4_t pkv[4];
        #pragma unroll
        for (int mt = 0; mt < 4; ++mt) {
            #pragma unroll
            for (int r = 0; r < 4; ++r)
                sa[mt][r] = __builtin_amdgcn_exp2f(sa[mt][r] - mnew);
            pkv[mt][0] = (__bf16)sa[mt][0]; pkv[mt][1] = (__bf16)sa[mt][1];
            pkv[mt][2] = (__bf16)sa[mt][2]; pkv[mt][3] = (__bf16)sa[mt][3];
        }
        f32x4_t sv = sa[0] + sa[1] + sa[2] + sa[3];
        float rs = (sv[0] + sv[1]) + (sv[2] + sv[3]);
        rs += __shfl_xor(rs, 16);
        rs += __shfl_xor(rs, 32);
        if (skip) {
            li += rs;
        } else {
            float a = __builtin_amdgcn_exp2f(mi - mnew);
            mi = mnew;
            li = li * a + rs;
            #pragma unroll
            for (int mt = 0; mt < 8; ++mt) {
                oacc[mt][0] *= a; oacc[mt][1] *= a;
                oacc[mt][2] *= a; oacc[mt][3] *= a;
            }
        }

        // ---- P (q-major) -> LDS: 4 x ds_write_b64, wave-local ----
        #pragma unroll
        for (int mt = 0; mt < 4; ++mt)
            *(bf16x4_t*)&pT_s[q_local * LDPT + mt * 16 + quad * 4] = pkv[mt];

        // ---- O^T += V^T P^T : 8 m-tiles (d) x 1 n-tile (q), k=64 ----
        __builtin_amdgcn_s_setprio(1);
        #pragma unroll
        for (int kc = 0; kc < 2; ++kc) {
            bf16x8_t pb = *(const bf16x8_t*)
                &pT_s[q_local * LDPT + kc * 32 + quad * 8];
            #pragma unroll
            for (int mt = 0; mt < 8; ++mt) {
                bf16x4_t vlo = *(const bf16x4_t*)
                    &vt_s[(mt * 16 + l16) * LDV + kc * 32 + quad * 8];
                bf16x4_t vhi = *(const bf16x4_t*)
                    &vt_s[(mt * 16 + l16) * LDV + kc * 32 + quad * 8 + 4];
                bf16x8_t vf = __builtin_shufflevector(vlo, vhi, 0,1,2,3,4,5,6,7);
                oacc[mt] = __builtin_amdgcn_mfma_f32_16x16x32_bf16(vf, pb, oacc[mt], 0, 0, 0);
            }
        }
        __builtin_amdgcn_s_setprio(0);
    }

    // ---- epilogue: two 64-row passes through the os overlay ----
    __syncthreads();               // all PV reads done before overlay
    const float inv = 1.0f / li;
    #pragma unroll
    for (int half = 0; half < 2; ++half) {
        if ((wave >> 2) == half) {
            const int orow = (wave & 3) * 16 + l16;   // q_local - half*64
            #pragma unroll
            for (int mt = 0; mt < 8; ++mt)
                #pragma unroll
                for (int r = 0; r < 4; ++r)
                    os[orow * LDOS + mt * 16 + quad * 4 + r] = oacc[mt][r] * inv;
        }
        __syncthreads();
        #pragma unroll
        for (int p = 0; p < 4; ++p) {
            int row = p * 16 + rK;                    // 0..63
            float4 f4 = *(const float4*)&os[row * LDOS + c4 * 4];
            *(float4*)&out[(size_t)(qt * BR + half * 64 + row) * DM + h * DHD + c4 * 4] = f4;
        }
        __syncthreads();
    }
}

extern "C" void kernel_launch(void* const* d_in, const int* in_sizes, int n_in,
                              void* d_out, int out_size, void* d_ws, size_t ws_size,
                              hipStream_t stream) {
    const float* q = (const float*)d_in[0];
    const float* k = (const float*)d_in[1];
    const float* v = (const float*)d_in[2];
    float* out = (float*)d_out;
    fa_fwd<<<dim3((SS / BR) * HH), dim3(512), 0, stream>>>(q, k, v, out);
}

// Round 7
// 289.640 us; speedup vs baseline: 1.2086x; 1.1440x over previous
//
#include <hip/hip_runtime.h>

#define HH 16
#define SS 4096
#define DHD 128
#define BR 64         // q rows per block (16 per wave)
#define BC 64         // k/v rows per tile
#define LDQS 136      // bf16/row for Q staging (prologue only)
#define LDQ 144       // fallback kernel k_s stride (R0-measured-good)
#define LDV 68        // fallback kernel vt_s stride
#define LDPT 72       // bf16/row for pT_s: 144B (16B-aligned)
#define LDOS 136      // f32/row for epilogue overlay
#define DM  (HH * DHD)

typedef __bf16 bf16x8_t __attribute__((ext_vector_type(8)));
typedef __bf16 bf16x4_t __attribute__((ext_vector_type(4)));
typedef float  f32x4_t  __attribute__((ext_vector_type(4)));

// lgkm-drain barrier (LDS-only sync; leaves global loads in flight)
#define BAR()  asm volatile("s_waitcnt lgkmcnt(0)\n\ts_barrier" ::: "memory")
// vm-drain barrier (global_load_lds landed; ds_reads already consumed pre-MFMA)
#define BARV() asm volatile("s_waitcnt vmcnt(0)\n\ts_barrier" ::: "memory")

typedef __attribute__((address_space(1))) const void gas_t;
typedef __attribute__((address_space(3))) void las_t;
__device__ __forceinline__ void gl16(const void* g, void* l) {
    __builtin_amdgcn_global_load_lds((gas_t*)g, (las_t*)l, 16, 0, 0);
}

__device__ __forceinline__ f32x4_t vmax4(f32x4_t a, f32x4_t b) {
    f32x4_t r;
    r[0] = fmaxf(a[0], b[0]); r[1] = fmaxf(a[1], b[1]);
    r[2] = fmaxf(a[2], b[2]); r[3] = fmaxf(a[3], b[3]);
    return r;
}

// ---------------- pre-pass: K -> bf16 tiles, swizzle baked ----------------
// Image: I_k[tile][row][e] = K[tile*64+row][ e ^ ((row&7)<<3) ]  (e in bf16 elems)
// so a b128 LDS read at byte (row*256 + colb) ^ ((row&7)<<4) returns K[row][colb/2..+8].
__global__ __launch_bounds__(256)
void prep_k(const float* __restrict__ k, __bf16* __restrict__ wk)
{
    const int c0 = (blockIdx.x * 256 + threadIdx.x) * 4;   // 16B-chunk index
    #pragma unroll
    for (int i = 0; i < 4; ++i) {
        const int c    = c0 + i;
        const int tile = c >> 10;            // 1024 chunks per 16KB tile
        const int o    = (c & 1023) * 16;    // byte offset in tile image
        const int row  = o >> 8;
        const int e0   = (o & 255) >> 1;     // 8-aligned element offset
        const int scol = e0 ^ ((row & 7) << 3);
        const float* src = k + (((size_t)(tile * 64 + row)) << 7) + scol;
        float4 a = ((const float4*)src)[0];
        float4 b = ((const float4*)src)[1];
        bf16x8_t bb;
        bb[0] = (__bf16)a.x; bb[1] = (__bf16)a.y; bb[2] = (__bf16)a.z; bb[3] = (__bf16)a.w;
        bb[4] = (__bf16)b.x; bb[5] = (__bf16)b.y; bb[6] = (__bf16)b.z; bb[7] = (__bf16)b.w;
        *(bf16x8_t*)((char*)wk + (size_t)c * 16) = bb;
    }
}

// ---------------- pre-pass: V -> V^T bf16 tiles, swizzle baked ----------------
// Image: I_v[tile][d][e] = V[tile*64 + (e ^ ((d&7)<<3))][d]  (e = k-col in tile)
__global__ __launch_bounds__(256)
void prep_v(const float* __restrict__ v, __bf16* __restrict__ wv)
{
    __shared__ __bf16 lt[64 * 132];          // staged tile [k][d], padded
    const int tile = blockIdx.x;
    const int tid  = threadIdx.x;
    #pragma unroll
    for (int i = 0; i < 8; ++i) {
        int idx = tid + i * 256;             // 0..2047 float4s
        int r = idx >> 5, cc = idx & 31;
        float4 val = ((const float4*)(v + (((size_t)(tile * 64 + r)) << 7)))[cc];
        bf16x4_t bb;
        bb[0] = (__bf16)val.x; bb[1] = (__bf16)val.y;
        bb[2] = (__bf16)val.z; bb[3] = (__bf16)val.w;
        *(bf16x4_t*)&lt[r * 132 + cc * 4] = bb;
    }
    __syncthreads();
    #pragma unroll
    for (int i = 0; i < 4; ++i) {
        int ch = tid * 4 + i;                // 0..1023 out 16B chunks
        int o  = ch * 8;                     // element offset in out tile
        int d  = o >> 6;
        int e0 = o & 63;
        int ks = e0 ^ ((d & 7) << 3);
        bf16x8_t bb;
        #pragma unroll
        for (int z = 0; z < 8; ++z) bb[z] = lt[(ks + z) * 132 + d];
        *(bf16x8_t*)((char*)wv + (size_t)tile * 16384 + (size_t)o * 2) = bb;
    }
}

// ---------------- main kernel: global_load_lds staging, dbuf, 1 barrier/iter ----------------
__global__ __launch_bounds__(256, 2)
void fa_fwd(const float* __restrict__ q, const __bf16* __restrict__ wk,
            const __bf16* __restrict__ wv, float* __restrict__ out)
{
    // 512 blocks: q-tile pair {g, 63-g} -> 66 iters each (R0-proven balance).
    const int L = blockIdx.x;
    const int h = L & 15;
    const int g = L >> 4;
    const int qts[2] = { g, 63 - g };

    const int tid  = threadIdx.x;
    const int wave = tid >> 6;
    const int lane = tid & 63;
    const int l16  = lane & 15;
    const int quad = lane >> 4;
    const int rK   = tid >> 5;
    const int c4   = tid & 31;
    const int swz  = (l16 & 7) << 4;       // byte XOR for swizzled K/V^T reads

    // smem: [kbuf0 16384][kbuf1 16384][vbuf0 16384][vbuf1 16384][pT 9216] = 74752.
    // Q staging (17408 B) overlays vbuf0+ (consumed to regs before first stage()).
    // Epilogue os overlay (34816 B) over kbufs (+2KB of vbuf0).
    __shared__ __align__(16) char smem[74752];
    unsigned short* pT_s = (unsigned short*)(smem + 65536);
    unsigned short* q_s  = (unsigned short*)(smem + 32768);
    float* os = (float*)smem;

    const float* qh = q + (size_t)h * SS * DHD;

    // stage k-tile j of this head into buffer b: pure LDS-DMA, no registers.
    auto stage = [&](int j, int b) {
        const size_t tb = ((size_t)(h * 64 + j)) * 16384;
        const char* gk = (const char*)wk + tb + wave * 4096 + lane * 16;
        const char* gv = (const char*)wv + tb + wave * 4096 + lane * 16;
        char* lk = smem + b * 16384 + wave * 4096;           // wave-uniform dest
        char* lv = smem + 32768 + b * 16384 + wave * 4096;
        #pragma unroll
        for (int c2 = 0; c2 < 4; ++c2) {
            gl16(gk + c2 * 1024, lk + c2 * 1024);
            gl16(gv + c2 * 1024, lv + c2 * 1024);
        }
    };

    // 1/sqrt(128) * log2(e): softmax in exp2 domain.
    const float scale = 0.088388347648318447f * 1.4426950408889634f;

    for (int t = 0; t < 2; ++t) {
        const int qt = qts[t];
        __syncthreads();               // prev tile's os/LDS reads done
        // ---- stage Q (scale folded) into q_s overlay ----
        #pragma unroll
        for (int i = 0; i < 8; ++i) {
            int idx = tid + i * 256;
            int r   = idx >> 5;
            int cc  = idx & 31;
            float4 val = ((const float4*)(qh + (size_t)(qt * BR + r) * DHD))[cc];
            bf16x4_t bb;
            bb[0] = (__bf16)(val.x * scale); bb[1] = (__bf16)(val.y * scale);
            bb[2] = (__bf16)(val.z * scale); bb[3] = (__bf16)(val.w * scale);
            *(bf16x4_t*)&q_s[r * LDQS + cc * 4] = bb;
        }
        __syncthreads();

        // ---- Q B-fragments (n-dim = wave's 16 q rows) ----
        bf16x8_t qf[4];
        #pragma unroll
        for (int kc = 0; kc < 4; ++kc)
            qf[kc] = *(const bf16x8_t*)
                &q_s[(wave * 16 + l16) * LDQS + kc * 32 + quad * 8];
        BAR();                          // q_s reads retired before loads overwrite vbuf

        stage(0, 0);                    // first k/v tile -> buf0

        f32x4_t oacc[8];                // O^T: row=d (8 m-tiles), col=q=l16
        #pragma unroll
        for (int mt = 0; mt < 8; ++mt) oacc[mt] = (f32x4_t)(0.0f);
        float mi = -INFINITY, li = 0.0f;

        const int q_local = wave * 16 + l16;

        for (int j = 0; j <= qt; ++j) {
            const int cur = j & 1;
            BARV();                     // tile j's LDS-DMA landed (all waves)
            if (j < qt) stage(j + 1, cur ^ 1);

            const char* kb = smem + cur * 16384;
            const char* vb = smem + 32768 + cur * 16384;

            // ---- S^T = K Q^T : 4 m-tiles (k-dim) x 1 n-tile (q) ----
            f32x4_t sa[4];
            #pragma unroll
            for (int mt = 0; mt < 4; ++mt) sa[mt] = (f32x4_t)(0.0f);
            __builtin_amdgcn_s_setprio(1);
            #pragma unroll
            for (int kc = 0; kc < 4; ++kc)
                #pragma unroll
                for (int mt = 0; mt < 4; ++mt) {
                    bf16x8_t kf = *(const bf16x8_t*)
                        (kb + (mt * 16 + l16) * 256 + ((kc * 64 + quad * 16) ^ swz));
                    sa[mt] = __builtin_amdgcn_mfma_f32_16x16x32_bf16(kf, qf[kc], sa[mt], 0, 0, 0);
                }
            __builtin_amdgcn_s_setprio(0);

            // ---- causal mask (diag tile only) ----
            if (j == qt) {
                #pragma unroll
                for (int mt = 0; mt < 4; ++mt)
                    #pragma unroll
                    for (int r = 0; r < 4; ++r)
                        if (mt * 16 + quad * 4 + r > q_local) sa[mt][r] = -INFINITY;
            }

            // ---- online softmax (exp2 domain): in-lane 16 + 2 shfls ----
            f32x4_t mv = vmax4(vmax4(sa[0], sa[1]), vmax4(sa[2], sa[3]));
            float mx = fmaxf(fmaxf(mv[0], mv[1]), fmaxf(mv[2], mv[3]));
            mx = fmaxf(mx, __shfl_xor(mx, 16));
            mx = fmaxf(mx, __shfl_xor(mx, 32));
            const bool skip = __all((int)(mx <= mi + 8.0f)) != 0;   // T13 defer-max
            const float mnew = skip ? mi : fmaxf(mi, mx);
            bf16x4_t pkv[4];
            #pragma unroll
            for (int mt = 0; mt < 4; ++mt) {
                #pragma unroll
                for (int r = 0; r < 4; ++r)
                    sa[mt][r] = __builtin_amdgcn_exp2f(sa[mt][r] - mnew);
                pkv[mt][0] = (__bf16)sa[mt][0]; pkv[mt][1] = (__bf16)sa[mt][1];
                pkv[mt][2] = (__bf16)sa[mt][2]; pkv[mt][3] = (__bf16)sa[mt][3];
            }
            f32x4_t sv = sa[0] + sa[1] + sa[2] + sa[3];
            float rs = (sv[0] + sv[1]) + (sv[2] + sv[3]);
            rs += __shfl_xor(rs, 16);
            rs += __shfl_xor(rs, 32);
            if (skip) {
                li += rs;
            } else {
                float a = __builtin_amdgcn_exp2f(mi - mnew);
                mi = mnew;
                li = li * a + rs;
                #pragma unroll
                for (int mt = 0; mt < 8; ++mt) {
                    oacc[mt][0] *= a; oacc[mt][1] *= a;
                    oacc[mt][2] *= a; oacc[mt][3] *= a;
                }
            }

            // ---- P (q-major) -> pT (wave-private rows): 4 x ds_write_b64 ----
            #pragma unroll
            for (int mt = 0; mt < 4; ++mt)
                *(bf16x4_t*)&pT_s[q_local * LDPT + mt * 16 + quad * 4] = pkv[mt];

            // ---- O^T += V^T P^T : 8 m-tiles (d) x 1 n-tile (q), k=64 ----
            __builtin_amdgcn_s_setprio(1);
            #pragma unroll
            for (int kc = 0; kc < 2; ++kc) {
                bf16x8_t pb = *(const bf16x8_t*)
                    &pT_s[q_local * LDPT + kc * 32 + quad * 8];
                #pragma unroll
                for (int mt = 0; mt < 8; ++mt) {
                    bf16x8_t vf = *(const bf16x8_t*)
                        (vb + (mt * 16 + l16) * 128 + ((kc * 64 + quad * 16) ^ swz));
                    oacc[mt] = __builtin_amdgcn_mfma_f32_16x16x32_bf16(vf, pb, oacc[mt], 0, 0, 0);
                }
            }
            __builtin_amdgcn_s_setprio(0);
        }

        // ---- epilogue: O^T -> LDS overlay -> coalesced fp32 store ----
        __syncthreads();
        float inv = 1.0f / li;
        #pragma unroll
        for (int mt = 0; mt < 8; ++mt)
            #pragma unroll
            for (int r = 0; r < 4; ++r)
                os[(wave * 16 + l16) * LDOS + mt * 16 + quad * 4 + r] = oacc[mt][r] * inv;
        __syncthreads();
        #pragma unroll
        for (int p = 0; p < 8; ++p) {
            int row = p * 8 + rK;
            float4 f4 = *(const float4*)&os[row * LDOS + c4 * 4];
            *(float4*)&out[(size_t)(qts[t] * BR + row) * DM + h * DHD + c4 * 4] = f4;
        }
    }
}

// ---------------- fallback (R0-proven, 183 us) if workspace too small ----------------
__global__ __launch_bounds__(256, 2)
void fa_fwd_fb(const float* __restrict__ q, const float* __restrict__ k,
               const float* __restrict__ v, float* __restrict__ out)
{
    const int L = blockIdx.x;
    const int h = L & 15;
    const int g = L >> 4;
    const int qts[2] = { g, 63 - g };

    const int tid  = threadIdx.x;
    const int wave = tid >> 6;
    const int lane = tid & 63;
    const int l16  = lane & 15;
    const int quad = lane >> 4;
    const int rK   = tid >> 5;
    const int c4   = tid & 31;
    const int dbase = (wave & 1) * 64;
    const int rbase = (wave >> 1) * 32;

    __shared__ __align__(16) char smem[63488];
    unsigned short* qp_s = (unsigned short*)smem;
    unsigned short* k_s  = (unsigned short*)(smem + 18432);
    unsigned short* vt_s = (unsigned short*)(smem + 36864);
    unsigned short* pT_s = (unsigned short*)(smem + 54272);
    float* os = (float*)smem;

    const size_t hoff = (size_t)h * SS * DHD;
    const float* qh = q + hoff;
    const float* kh = k + hoff;
    const float* vh = v + hoff;

    float4 kreg[8];
    float  vreg[8][4];
    auto issue = [&](int j) {
        const float* kb = kh + (size_t)j * BC * DHD;
        #pragma unroll
        for (int i = 0; i < 8; ++i)
            kreg[i] = ((const float4*)(kb + (size_t)(rK + i * 8) * DHD))[c4];
        const float* vb = vh + (size_t)j * BC * DHD + dbase + lane;
        #pragma unroll
        for (int p = 0; p < 8; ++p) {
            const float* vp = vb + (size_t)(rbase + p * 4) * DHD;
            vreg[p][0] = vp[0];
            vreg[p][1] = vp[DHD];
            vreg[p][2] = vp[2 * DHD];
            vreg[p][3] = vp[3 * DHD];
        }
    };

    const float scale = 0.088388347648318447f;
    issue(0);

    for (int t = 0; t < 2; ++t) {
        const int qt = qts[t];
        __syncthreads();
        #pragma unroll
        for (int i = 0; i < 8; ++i) {
            int idx = tid + i * 256;
            int r   = idx >> 5;
            int cc  = idx & 31;
            float4 val = ((const float4*)(qh + (size_t)(qt * BR + r) * DHD))[cc];
            bf16x4_t bb;
            bb[0] = (__bf16)(val.x * scale); bb[1] = (__bf16)(val.y * scale);
            bb[2] = (__bf16)(val.z * scale); bb[3] = (__bf16)(val.w * scale);
            *(bf16x4_t*)&qp_s[r * LDQ + cc * 4] = bb;
        }
        __syncthreads();

        bf16x8_t qf[4];
        #pragma unroll
        for (int kc = 0; kc < 4; ++kc)
            qf[kc] = *(const bf16x8_t*)
                &qp_s[(wave * 16 + l16) * LDQ + kc * 32 + quad * 8];

        f32x4_t oacc[8];
        #pragma unroll
        for (int mt = 0; mt < 8; ++mt) oacc[mt] = (f32x4_t)(0.0f);
        float mi = -INFINITY, li = 0.0f;
        const int q_local = wave * 16 + l16;

        for (int j = 0; j <= qt; ++j) {
            BAR();
            #pragma unroll
            for (int i = 0; i < 8; ++i) {
                bf16x4_t bb;
                bb[0] = (__bf16)kreg[i].x; bb[1] = (__bf16)kreg[i].y;
                bb[2] = (__bf16)kreg[i].z; bb[3] = (__bf16)kreg[i].w;
                *(bf16x4_t*)&k_s[(rK + i * 8) * LDQ + c4 * 4] = bb;
            }
            #pragma unroll
            for (int p = 0; p < 8; ++p) {
                bf16x4_t bb;
                bb[0] = (__bf16)vreg[p][0]; bb[1] = (__bf16)vreg[p][1];
                bb[2] = (__bf16)vreg[p][2]; bb[3] = (__bf16)vreg[p][3];
                *(bf16x4_t*)&vt_s[(dbase + lane) * LDV + rbase + p * 4] = bb;
            }
            if (j < qt)      issue(j + 1);
            else if (t == 0) issue(0);
            BAR();

            f32x4_t sa[4];
            #pragma unroll
            for (int mt = 0; mt < 4; ++mt) sa[mt] = (f32x4_t)(0.0f);
            #pragma unroll
            for (int kc = 0; kc < 4; ++kc)
                #pragma unroll
                for (int mt = 0; mt < 4; ++mt) {
                    bf16x8_t kf = *(const bf16x8_t*)
                        &k_s[(mt * 16 + l16) * LDQ + kc * 32 + quad * 8];
                    sa[mt] = __builtin_amdgcn_mfma_f32_16x16x32_bf16(kf, qf[kc], sa[mt], 0, 0, 0);
                }

            if (j == qt) {
                #pragma unroll
                for (int mt = 0; mt < 4; ++mt)
                    #pragma unroll
                    for (int r = 0; r < 4; ++r)
                        if (mt * 16 + quad * 4 + r > q_local) sa[mt][r] = -INFINITY;
            }

            f32x4_t mv = vmax4(vmax4(sa[0], sa[1]), vmax4(sa[2], sa[3]));
            float mx = fmaxf(fmaxf(mv[0], mv[1]), fmaxf(mv[2], mv[3]));
            mx = fmaxf(mx, __shfl_xor(mx, 16));
            mx = fmaxf(mx, __shfl_xor(mx, 32));
            float mnew = fmaxf(mi, mx);
            float a = __expf(mi - mnew);
            mi = mnew;
            bf16x4_t pkv[4];
            #pragma unroll
            for (int mt = 0; mt < 4; ++mt) {
                #pragma unroll
                for (int r = 0; r < 4; ++r) sa[mt][r] = __expf(sa[mt][r] - mnew);
                pkv[mt][0] = (__bf16)sa[mt][0]; pkv[mt][1] = (__bf16)sa[mt][1];
                pkv[mt][2] = (__bf16)sa[mt][2]; pkv[mt][3] = (__bf16)sa[mt][3];
            }
            f32x4_t sv = sa[0] + sa[1] + sa[2] + sa[3];
            float rs = (sv[0] + sv[1]) + (sv[2] + sv[3]);
            rs += __shfl_xor(rs, 16);
            rs += __shfl_xor(rs, 32);
            li = li * a + rs;

            #pragma unroll
            for (int mt = 0; mt < 4; ++mt)
                *(bf16x4_t*)&pT_s[(wave * 16 + l16) * LDPT + mt * 16 + quad * 4] = pkv[mt];

            #pragma unroll
            for (int mt = 0; mt < 8; ++mt) {
                oacc[mt][0] *= a; oacc[mt][1] *= a;
                oacc[mt][2] *= a; oacc[mt][3] *= a;
            }

            #pragma unroll
            for (int kc = 0; kc < 2; ++kc) {
                bf16x8_t pb = *(const bf16x8_t*)
                    &pT_s[(wave * 16 + l16) * LDPT + kc * 32 + quad * 8];
                #pragma unroll
                for (int mt = 0; mt < 8; ++mt) {
                    bf16x4_t vlo = *(const bf16x4_t*)
                        &vt_s[(mt * 16 + l16) * LDV + kc * 32 + quad * 8];
                    bf16x4_t vhi = *(const bf16x4_t*)
                        &vt_s[(mt * 16 + l16) * LDV + kc * 32 + quad * 8 + 4];
                    bf16x8_t vf = __builtin_shufflevector(vlo, vhi, 0,1,2,3,4,5,6,7);
                    oacc[mt] = __builtin_amdgcn_mfma_f32_16x16x32_bf16(vf, pb, oacc[mt], 0, 0, 0);
                }
            }
        }

        __syncthreads();
        float inv = 1.0f / li;
        #pragma unroll
        for (int mt = 0; mt < 8; ++mt)
            #pragma unroll
            for (int r = 0; r < 4; ++r)
                os[(wave * 16 + l16) * LDOS + mt * 16 + quad * 4 + r] = oacc[mt][r] * inv;
        __syncthreads();
        #pragma unroll
        for (int p = 0; p < 8; ++p) {
            int row = p * 8 + rK;
            float4 f4 = *(const float4*)&os[row * LDOS + c4 * 4];
            *(float4*)&out[(size_t)(qt * BR + row) * DM + h * DHD + c4 * 4] = f4;
        }
    }
}

extern "C" void kernel_launch(void* const* d_in, const int* in_sizes, int n_in,
                              void* d_out, int out_size, void* d_ws, size_t ws_size,
                              hipStream_t stream) {
    const float* q = (const float*)d_in[0];
    const float* k = (const float*)d_in[1];
    const float* v = (const float*)d_in[2];
    float* out = (float*)d_out;
    if (d_ws != nullptr && ws_size >= (size_t)33554432) {
        __bf16* wk = (__bf16*)d_ws;
        __bf16* wv = (__bf16*)((char*)d_ws + 16777216);
        prep_k<<<dim3(1024), dim3(256), 0, stream>>>(k, wk);
        prep_v<<<dim3(1024), dim3(256), 0, stream>>>(v, wv);
        fa_fwd<<<dim3((SS / BR / 2) * HH), dim3(256), 0, stream>>>(q, wk, wv, out);
    } else {
        fa_fwd_fb<<<dim3((SS / BR / 2) * HH), dim3(256), 0, stream>>>(q, k, v, out);
    }
}

// Round 9
// 271.274 us; speedup vs baseline: 1.2904x; 1.0677x over previous
//
#include <hip/hip_runtime.h>

#define HH 16
#define SS 4096
#define DHD 128
#define BR 64         // q rows per block (16 per wave)
#define BC 64         // k/v rows per tile
#define LDQS 136      // bf16/row for Q staging (prologue only)
#define LDQ 144       // fallback kernel k_s stride (R0-measured-good)
#define LDV 68        // fallback kernel vt_s stride
#define LDPT 72       // bf16/row for pT_s: 144B (16B-aligned)
#define LDOS 136      // f32/row for epilogue overlay
#define DM  (HH * DHD)
#define KTILE 16384

typedef __bf16 bf16x8_t __attribute__((ext_vector_type(8)));
typedef __bf16 bf16x4_t __attribute__((ext_vector_type(4)));
typedef float  f32x4_t  __attribute__((ext_vector_type(4)));

// lgkm-drain barrier (LDS-only sync; leaves global loads in flight)
#define BAR()  asm volatile("s_waitcnt lgkmcnt(0)\n\ts_barrier" ::: "memory")
// vm-drain barrier (global_load_lds landed; issued a full iteration earlier)
#define BARV() asm volatile("s_waitcnt vmcnt(0)\n\ts_barrier" ::: "memory")

typedef __attribute__((address_space(1))) const void gas_t;
typedef __attribute__((address_space(3))) void las_t;
__device__ __forceinline__ void gl16(const void* g, void* l) {
    __builtin_amdgcn_global_load_lds((gas_t*)g, (las_t*)l, 16, 0, 0);
}

__device__ __forceinline__ f32x4_t vmax4(f32x4_t a, f32x4_t b) {
    f32x4_t r;
    r[0] = fmaxf(a[0], b[0]); r[1] = fmaxf(a[1], b[1]);
    r[2] = fmaxf(a[2], b[2]); r[3] = fmaxf(a[3], b[3]);
    return r;
}

// ---------------- pre-pass: K -> bf16 tiles, swizzle baked (R7-proven) ----------------
__global__ __launch_bounds__(256)
void prep_k(const float* __restrict__ k, __bf16* __restrict__ wk)
{
    const int c0 = (blockIdx.x * 256 + threadIdx.x) * 4;   // 16B-chunk index
    #pragma unroll
    for (int i = 0; i < 4; ++i) {
        const int c    = c0 + i;
        const int tile = c >> 10;            // 1024 chunks per 16KB tile
        const int o    = (c & 1023) * 16;    // byte offset in tile image
        const int row  = o >> 8;
        const int e0   = (o & 255) >> 1;     // 8-aligned element offset
        const int scol = e0 ^ ((row & 7) << 3);
        const float* src = k + (((size_t)(tile * 64 + row)) << 7) + scol;
        float4 a = ((const float4*)src)[0];
        float4 b = ((const float4*)src)[1];
        bf16x8_t bb;
        bb[0] = (__bf16)a.x; bb[1] = (__bf16)a.y; bb[2] = (__bf16)a.z; bb[3] = (__bf16)a.w;
        bb[4] = (__bf16)b.x; bb[5] = (__bf16)b.y; bb[6] = (__bf16)b.z; bb[7] = (__bf16)b.w;
        *(bf16x8_t*)((char*)wk + (size_t)c * 16) = bb;
    }
}

// ---------------- pre-pass: V -> V^T bf16 tiles, swizzle baked (R7-proven) ----------------
__global__ __launch_bounds__(256)
void prep_v(const float* __restrict__ v, __bf16* __restrict__ wv)
{
    __shared__ __bf16 lt[64 * 132];          // staged tile [k][d], padded
    const int tile = blockIdx.x;
    const int tid  = threadIdx.x;
    #pragma unroll
    for (int i = 0; i < 8; ++i) {
        int idx = tid + i * 256;             // 0..2047 float4s
        int r = idx >> 5, cc = idx & 31;
        float4 val = ((const float4*)(v + (((size_t)(tile * 64 + r)) << 7)))[cc];
        bf16x4_t bb;
        bb[0] = (__bf16)val.x; bb[1] = (__bf16)val.y;
        bb[2] = (__bf16)val.z; bb[3] = (__bf16)val.w;
        *(bf16x4_t*)&lt[r * 132 + cc * 4] = bb;
    }
    __syncthreads();
    #pragma unroll
    for (int i = 0; i < 4; ++i) {
        int ch = tid * 4 + i;                // 0..1023 out 16B chunks
        int o  = ch * 8;                     // element offset in out tile
        int d  = o >> 6;
        int e0 = o & 63;
        int ks = e0 ^ ((d & 7) << 3);
        bf16x8_t bb;
        #pragma unroll
        for (int z = 0; z < 8; ++z) bb[z] = lt[(ks + z) * 132 + d];
        *(bf16x8_t*)((char*)wv + (size_t)tile * 16384 + (size_t)o * 2) = bb;
    }
}

// ---------------- main kernel: R7 memory system + software-pipelined schedule ----------------
// Iter j: issue DMA K[j+2]/V[j+1]; QK(j+1) MFMAs (independent) overlap softmax(j)+PV(j).
// K staged distance-2 into kb[j&1] (dead since QK(j) last iter); V distance-1.
// One vmcnt(0)+barrier per iter. Softmax: per-lane partial li (quad-summed once at
// end); T13 vote on per-lane max -> no shfls on the common path.
__global__ __launch_bounds__(256, 2)
void fa_fwd(const float* __restrict__ q, const __bf16* __restrict__ wk,
            const __bf16* __restrict__ wv, float* __restrict__ out)
{
    // 512 blocks: q-tile pair {g, 63-g} -> 66 iters each (R0-proven balance).
    const int L = blockIdx.x;
    const int h = L & 15;
    const int g = L >> 4;
    const int qts[2] = { g, 63 - g };

    const int tid  = threadIdx.x;
    const int wave = tid >> 6;
    const int lane = tid & 63;
    const int l16  = lane & 15;
    const int quad = lane >> 4;
    const int rK   = tid >> 5;
    const int c4   = tid & 31;
    const int swz  = (l16 & 7) << 4;       // byte XOR for swizzled K/V^T reads

    // smem: [kbuf0 16384][kbuf1 16384][vbuf0 16384][vbuf1 16384][pT 9216] = 74752.
    // Q staging (17408 B) overlays vbuf0+ (consumed to regs before first stageV).
    // Epilogue os overlay (34816 B) over kbufs.
    __shared__ __align__(16) char smem[74752];
    unsigned short* pT_s = (unsigned short*)(smem + 65536);
    unsigned short* q_s  = (unsigned short*)(smem + 32768);
    float* os = (float*)smem;

    const float* qh = q + (size_t)h * SS * DHD;

    auto stageK = [&](int j, int b) {
        const char* gk = (const char*)wk + ((size_t)(h * 64 + j)) * KTILE + wave * 4096 + lane * 16;
        char* lk = smem + b * KTILE + wave * 4096;          // wave-uniform dest
        #pragma unroll
        for (int c2 = 0; c2 < 4; ++c2) gl16(gk + c2 * 1024, lk + c2 * 1024);
    };
    auto stageV = [&](int j, int b) {
        const char* gv = (const char*)wv + ((size_t)(h * 64 + j)) * KTILE + wave * 4096 + lane * 16;
        char* lv = smem + 32768 + b * KTILE + wave * 4096;
        #pragma unroll
        for (int c2 = 0; c2 < 4; ++c2) gl16(gv + c2 * 1024, lv + c2 * 1024);
    };

    // 1/sqrt(128) * log2(e): softmax in exp2 domain.
    const float scale = 0.088388347648318447f * 1.4426950408889634f;

#define ITER(SC, SN) do {                                                     \
    if (j + 2 <= qt) stageK(j + 2, j & 1);                                    \
    if (j + 1 <= qt) stageV(j + 1, (j + 1) & 1);                              \
    if (j < qt) {                                                             \
        const char* kbp = smem + ((j + 1) & 1) * KTILE;                       \
        _Pragma("unroll")                                                     \
        for (int mt = 0; mt < 4; ++mt) SN[mt] = (f32x4_t)(0.0f);              \
        __builtin_amdgcn_s_setprio(1);                                        \
        _Pragma("unroll")                                                     \
        for (int kc = 0; kc < 4; ++kc)                                        \
            _Pragma("unroll")                                                 \
            for (int mt = 0; mt < 4; ++mt) {                                  \
                bf16x8_t kf = *(const bf16x8_t*)                              \
                    (kbp + (mt * 16 + l16) * 256 + ((kc * 64 + quad * 16) ^ swz)); \
                SN[mt] = __builtin_amdgcn_mfma_f32_16x16x32_bf16(kf, qf[kc], SN[mt], 0, 0, 0); \
            }                                                                 \
        __builtin_amdgcn_s_setprio(0);                                        \
    }                                                                         \
    if (j == qt) {                                                            \
        _Pragma("unroll")                                                     \
        for (int mt = 0; mt < 4; ++mt)                                        \
            _Pragma("unroll")                                                 \
            for (int r = 0; r < 4; ++r)                                       \
                if (mt * 16 + quad * 4 + r > q_local) SC[mt][r] = -INFINITY;  \
    }                                                                         \
    f32x4_t mv = vmax4(vmax4(SC[0], SC[1]), vmax4(SC[2], SC[3]));             \
    float mxl = fmaxf(fmaxf(mv[0], mv[1]), fmaxf(mv[2], mv[3]));              \
    const bool skip = __all((int)(mxl <= mi + 8.0f)) != 0;                    \
    float mnew = mi;                                                          \
    if (!skip) {                                                              \
        float mr = fmaxf(mxl, __shfl_xor(mxl, 16));                           \
        mr = fmaxf(mr, __shfl_xor(mr, 32));                                   \
        mnew = fmaxf(mi, mr);                                                 \
        float a = __builtin_amdgcn_exp2f(mi - mnew);                          \
        mi = mnew;                                                            \
        li *= a;                                                              \
        _Pragma("unroll")                                                     \
        for (int mt = 0; mt < 8; ++mt) {                                      \
            oacc[mt][0] *= a; oacc[mt][1] *= a;                               \
            oacc[mt][2] *= a; oacc[mt][3] *= a;                               \
        }                                                                     \
    }                                                                         \
    bf16x4_t pkv[4];                                                          \
    _Pragma("unroll")                                                         \
    for (int mt = 0; mt < 4; ++mt) {                                          \
        _Pragma("unroll")                                                     \
        for (int r = 0; r < 4; ++r)                                           \
            SC[mt][r] = __builtin_amdgcn_exp2f(SC[mt][r] - mnew);             \
        pkv[mt][0] = (__bf16)SC[mt][0]; pkv[mt][1] = (__bf16)SC[mt][1];       \
        pkv[mt][2] = (__bf16)SC[mt][2]; pkv[mt][3] = (__bf16)SC[mt][3];       \
        *(bf16x4_t*)&pT_s[q_local * LDPT + mt * 16 + quad * 4] = pkv[mt];     \
    }                                                                         \
    f32x4_t sv = SC[0] + SC[1] + SC[2] + SC[3];                               \
    li += (sv[0] + sv[1]) + (sv[2] + sv[3]);                                  \
    {                                                                         \
        const char* vbp = smem + 32768 + (j & 1) * KTILE;                     \
        __builtin_amdgcn_s_setprio(1);                                        \
        _Pragma("unroll")                                                     \
        for (int kc = 0; kc < 2; ++kc) {                                      \
            bf16x8_t pb = *(const bf16x8_t*)&pT_s[q_local * LDPT + kc * 32 + quad * 8]; \
            _Pragma("unroll")                                                 \
            for (int mt = 0; mt < 8; ++mt) {                                  \
                bf16x8_t vf = *(const bf16x8_t*)                              \
                    (vbp + (mt * 16 + l16) * 128 + ((kc * 64 + quad * 16) ^ swz)); \
                oacc[mt] = __builtin_amdgcn_mfma_f32_16x16x32_bf16(vf, pb, oacc[mt], 0, 0, 0); \
            }                                                                 \
        }                                                                     \
        __builtin_amdgcn_s_setprio(0);                                        \
    }                                                                         \
    BARV();                                                                   \
} while (0)

    for (int t = 0; t < 2; ++t) {
        const int qt = qts[t];
        __syncthreads();               // prev tile's os/LDS reads done
        // ---- issue K0/K1 DMA early (latency covered by Q staging) ----
        stageK(0, 0);
        stageK(1, 1);
        // ---- stage Q (scale folded) into q_s overlay ----
        #pragma unroll
        for (int i = 0; i < 8; ++i) {
            int idx = tid + i * 256;
            int r   = idx >> 5;
            int cc  = idx & 31;
            float4 val = ((const float4*)(qh + (size_t)(qt * BR + r) * DHD))[cc];
            bf16x4_t bb;
            bb[0] = (__bf16)(val.x * scale); bb[1] = (__bf16)(val.y * scale);
            bb[2] = (__bf16)(val.z * scale); bb[3] = (__bf16)(val.w * scale);
            *(bf16x4_t*)&q_s[r * LDQS + cc * 4] = bb;
        }
        __syncthreads();

        // ---- Q B-fragments ----
        bf16x8_t qf[4];
        #pragma unroll
        for (int kc = 0; kc < 4; ++kc)
            qf[kc] = *(const bf16x8_t*)
                &q_s[(wave * 16 + l16) * LDQS + kc * 32 + quad * 8];
        BAR();                          // q_s reads retired before V0 DMA overwrites
        stageV(0, 0);

        f32x4_t oacc[8];
        #pragma unroll
        for (int mt = 0; mt < 8; ++mt) oacc[mt] = (f32x4_t)(0.0f);
        float mi = -INFINITY, li = 0.0f;
        const int q_local = wave * 16 + l16;

        BARV();                         // K0, K1, V0 landed (all waves)

        // ---- prologue: QK(0) -> sA ----
        f32x4_t sA[4], sB[4];
        {
            const char* kbp = smem;     // kb0
            #pragma unroll
            for (int mt = 0; mt < 4; ++mt) sA[mt] = (f32x4_t)(0.0f);
            __builtin_amdgcn_s_setprio(1);
            #pragma unroll
            for (int kc = 0; kc < 4; ++kc)
                #pragma unroll
                for (int mt = 0; mt < 4; ++mt) {
                    bf16x8_t kf = *(const bf16x8_t*)
                        (kbp + (mt * 16 + l16) * 256 + ((kc * 64 + quad * 16) ^ swz));
                    sA[mt] = __builtin_amdgcn_mfma_f32_16x16x32_bf16(kf, qf[kc], sA[mt], 0, 0, 0);
                }
            __builtin_amdgcn_s_setprio(0);
        }

        int j = 0;
        for (;;) {
            ITER(sA, sB);
            if (j == qt) break; ++j;
            ITER(sB, sA);
            if (j == qt) break; ++j;
        }

        // ---- li quad-reduction (deferred from the loop): 2 shfls once ----
        li += __shfl_xor(li, 16);
        li += __shfl_xor(li, 32);

        // ---- epilogue: O^T -> LDS overlay -> coalesced fp32 store ----
        __syncthreads();
        float inv = 1.0f / li;
        #pragma unroll
        for (int mt = 0; mt < 8; ++mt)
            #pragma unroll
            for (int r = 0; r < 4; ++r)
                os[(wave * 16 + l16) * LDOS + mt * 16 + quad * 4 + r] = oacc[mt][r] * inv;
        __syncthreads();
        #pragma unroll
        for (int p = 0; p < 8; ++p) {
            int row = p * 8 + rK;
            float4 f4 = *(const float4*)&os[row * LDOS + c4 * 4];
            *(float4*)&out[(size_t)(qt * BR + row) * DM + h * DHD + c4 * 4] = f4;
        }
    }
#undef ITER
}

// ---------------- fallback (R0-proven, 183 us) if workspace too small ----------------
__global__ __launch_bounds__(256, 2)
void fa_fwd_fb(const float* __restrict__ q, const float* __restrict__ k,
               const float* __restrict__ v, float* __restrict__ out)
{
    const int L = blockIdx.x;
    const int h = L & 15;
    const int g = L >> 4;
    const int qts[2] = { g, 63 - g };

    const int tid  = threadIdx.x;
    const int wave = tid >> 6;
    const int lane = tid & 63;
    const int l16  = lane & 15;
    const int quad = lane >> 4;
    const int rK   = tid >> 5;
    const int c4   = tid & 31;
    const int dbase = (wave & 1) * 64;
    const int rbase = (wave >> 1) * 32;

    __shared__ __align__(16) char smem[63488];
    unsigned short* qp_s = (unsigned short*)smem;
    unsigned short* k_s  = (unsigned short*)(smem + 18432);
    unsigned short* vt_s = (unsigned short*)(smem + 36864);
    unsigned short* pT_s = (unsigned short*)(smem + 54272);
    float* os = (float*)smem;

    const size_t hoff = (size_t)h * SS * DHD;
    const float* qh = q + hoff;
    const float* kh = k + hoff;
    const float* vh = v + hoff;

    float4 kreg[8];
    float  vreg[8][4];
    auto issue = [&](int j) {
        const float* kb = kh + (size_t)j * BC * DHD;
        #pragma unroll
        for (int i = 0; i < 8; ++i)
            kreg[i] = ((const float4*)(kb + (size_t)(rK + i * 8) * DHD))[c4];
        const float* vb = vh + (size_t)j * BC * DHD + dbase + lane;
        #pragma unroll
        for (int p = 0; p < 8; ++p) {
            const float* vp = vb + (size_t)(rbase + p * 4) * DHD;
            vreg[p][0] = vp[0];
            vreg[p][1] = vp[DHD];
            vreg[p][2] = vp[2 * DHD];
            vreg[p][3] = vp[3 * DHD];
        }
    };

    const float scale = 0.088388347648318447f;
    issue(0);

    for (int t = 0; t < 2; ++t) {
        const int qt = qts[t];
        __syncthreads();
        #pragma unroll
        for (int i = 0; i < 8; ++i) {
            int idx = tid + i * 256;
            int r   = idx >> 5;
            int cc  = idx & 31;
            float4 val = ((const float4*)(qh + (size_t)(qt * BR + r) * DHD))[cc];
            bf16x4_t bb;
            bb[0] = (__bf16)(val.x * scale); bb[1] = (__bf16)(val.y * scale);
            bb[2] = (__bf16)(val.z * scale); bb[3] = (__bf16)(val.w * scale);
            *(bf16x4_t*)&qp_s[r * LDQ + cc * 4] = bb;
        }
        __syncthreads();

        bf16x8_t qf[4];
        #pragma unroll
        for (int kc = 0; kc < 4; ++kc)
            qf[kc] = *(const bf16x8_t*)
                &qp_s[(wave * 16 + l16) * LDQ + kc * 32 + quad * 8];

        f32x4_t oacc[8];
        #pragma unroll
        for (int mt = 0; mt < 8; ++mt) oacc[mt] = (f32x4_t)(0.0f);
        float mi = -INFINITY, li = 0.0f;
        const int q_local = wave * 16 + l16;

        for (int j = 0; j <= qt; ++j) {
            BAR();
            #pragma unroll
            for (int i = 0; i < 8; ++i) {
                bf16x4_t bb;
                bb[0] = (__bf16)kreg[i].x; bb[1] = (__bf16)kreg[i].y;
                bb[2] = (__bf16)kreg[i].z; bb[3] = (__bf16)kreg[i].w;
                *(bf16x4_t*)&k_s[(rK + i * 8) * LDQ + c4 * 4] = bb;
            }
            #pragma unroll
            for (int p = 0; p < 8; ++p) {
                bf16x4_t bb;
                bb[0] = (__bf16)vreg[p][0]; bb[1] = (__bf16)vreg[p][1];
                bb[2] = (__bf16)vreg[p][2]; bb[3] = (__bf16)vreg[p][3];
                *(bf16x4_t*)&vt_s[(dbase + lane) * LDV + rbase + p * 4] = bb;
            }
            if (j < qt)      issue(j + 1);
            else if (t == 0) issue(0);
            BAR();

            f32x4_t sa[4];
            #pragma unroll
            for (int mt = 0; mt < 4; ++mt) sa[mt] = (f32x4_t)(0.0f);
            #pragma unroll
            for (int kc = 0; kc < 4; ++kc)
                #pragma unroll
                for (int mt = 0; mt < 4; ++mt) {
                    bf16x8_t kf = *(const bf16x8_t*)
                        &k_s[(mt * 16 + l16) * LDQ + kc * 32 + quad * 8];
                    sa[mt] = __builtin_amdgcn_mfma_f32_16x16x32_bf16(kf, qf[kc], sa[mt], 0, 0, 0);
                }

            if (j == qt) {
                #pragma unroll
                for (int mt = 0; mt < 4; ++mt)
                    #pragma unroll
                    for (int r = 0; r < 4; ++r)
                        if (mt * 16 + quad * 4 + r > q_local) sa[mt][r] = -INFINITY;
            }

            f32x4_t mv = vmax4(vmax4(sa[0], sa[1]), vmax4(sa[2], sa[3]));
            float mx = fmaxf(fmaxf(mv[0], mv[1]), fmaxf(mv[2], mv[3]));
            mx = fmaxf(mx, __shfl_xor(mx, 16));
            mx = fmaxf(mx, __shfl_xor(mx, 32));
            float mnew = fmaxf(mi, mx);
            float a = __expf(mi - mnew);
            mi = mnew;
            bf16x4_t pkv[4];
            #pragma unroll
            for (int mt = 0; mt < 4; ++mt) {
                #pragma unroll
                for (int r = 0; r < 4; ++r) sa[mt][r] = __expf(sa[mt][r] - mnew);
                pkv[mt][0] = (__bf16)sa[mt][0]; pkv[mt][1] = (__bf16)sa[mt][1];
                pkv[mt][2] = (__bf16)sa[mt][2]; pkv[mt][3] = (__bf16)sa[mt][3];
            }
            f32x4_t sv = sa[0] + sa[1] + sa[2] + sa[3];
            float rs = (sv[0] + sv[1]) + (sv[2] + sv[3]);
            rs += __shfl_xor(rs, 16);
            rs += __shfl_xor(rs, 32);
            li = li * a + rs;

            #pragma unroll
            for (int mt = 0; mt < 4; ++mt)
                *(bf16x4_t*)&pT_s[(wave * 16 + l16) * LDPT + mt * 16 + quad * 4] = pkv[mt];

            #pragma unroll
            for (int mt = 0; mt < 8; ++mt) {
                oacc[mt][0] *= a; oacc[mt][1] *= a;
                oacc[mt][2] *= a; oacc[mt][3] *= a;
            }

            #pragma unroll
            for (int kc = 0; kc < 2; ++kc) {
                bf16x8_t pb = *(const bf16x8_t*)
                    &pT_s[(wave * 16 + l16) * LDPT + kc * 32 + quad * 8];
                #pragma unroll
                for (int mt = 0; mt < 8; ++mt) {
                    bf16x4_t vlo = *(const bf16x4_t*)
                        &vt_s[(mt * 16 + l16) * LDV + kc * 32 + quad * 8];
                    bf16x4_t vhi = *(const bf16x4_t*)
                        &vt_s[(mt * 16 + l16) * LDV + kc * 32 + quad * 8 + 4];
                    bf16x8_t vf = __builtin_shufflevector(vlo, vhi, 0,1,2,3,4,5,6,7);
                    oacc[mt] = __builtin_amdgcn_mfma_f32_16x16x32_bf16(vf, pb, oacc[mt], 0, 0, 0);
                }
            }
        }

        __syncthreads();
        float inv = 1.0f / li;
        #pragma unroll
        for (int mt = 0; mt < 8; ++mt)
            #pragma unroll
            for (int r = 0; r < 4; ++r)
                os[(wave * 16 + l16) * LDOS + mt * 16 + quad * 4 + r] = oacc[mt][r] * inv;
        __syncthreads();
        #pragma unroll
        for (int p = 0; p < 8; ++p) {
            int row = p * 8 + rK;
            float4 f4 = *(const float4*)&os[row * LDOS + c4 * 4];
            *(float4*)&out[(size_t)(qt * BR + row) * DM + h * DHD + c4 * 4] = f4;
        }
    }
}

extern "C" void kernel_launch(void* const* d_in, const int* in_sizes, int n_in,
                              void* d_out, int out_size, void* d_ws, size_t ws_size,
                              hipStream_t stream) {
    const float* q = (const float*)d_in[0];
    const float* k = (const float*)d_in[1];
    const float* v = (const float*)d_in[2];
    float* out = (float*)d_out;
    if (d_ws != nullptr && ws_size >= (size_t)33554432) {
        __bf16* wk = (__bf16*)d_ws;
        __bf16* wv = (__bf16*)((char*)d_ws + 16777216);
        prep_k<<<dim3(1024), dim3(256), 0, stream>>>(k, wk);
        prep_v<<<dim3(1024), dim3(256), 0, stream>>>(v, wv);
        fa_fwd<<<dim3((SS / BR / 2) * HH), dim3(256), 0, stream>>>(q, wk, wv, out);
    } else {
        fa_fwd_fb<<<dim3((SS / BR / 2) * HH), dim3(256), 0, stream>>>(q, k, v, out);
    }
}